// Round 5
// baseline (268.277 us; speedup 1.0000x reference)
//
#include <hip/hip_runtime.h>
#include <hip/hip_bf16.h>

// ---------------------------------------------------------------------------
// MultiHeadAttention: x(B,T,C) fp32 -> out(B,T,C) fp32
// B=4 T=2048 C=1024 H=16 D=64. Internally bf16 MFMA with fp32 accumulation.
// Pipeline: convert -> fused QKV GEMM -> pipelined causal flash attn -> out GEMM.
// ---------------------------------------------------------------------------

#define B_  4
#define T_  2048
#define C_  1024
#define H_  16
#define D_  64
#define M_  (B_*T_)   // 8192 rows for the projection GEMMs

#define LOG2E 1.4426950408889634f

using bf16x8 = __attribute__((ext_vector_type(8))) short;
using f32x4  = __attribute__((ext_vector_type(4))) float;
using u16x4  = __attribute__((ext_vector_type(4))) unsigned short;

__device__ __forceinline__ unsigned short f2bf(float f) {
  union { float f; unsigned u; } cv; cv.f = f;
  unsigned u = cv.u;
  u += 0x7fffu + ((u >> 16) & 1u);   // RNE (inputs are finite)
  return (unsigned short)(u >> 16);
}

// pack two f32 -> one dword of 2 bf16 (RNE), single VALU op
__device__ __forceinline__ unsigned cvt_pk_bf16(float lo, float hi) {
  unsigned r;
  asm("v_cvt_pk_bf16_f32 %0, %1, %2" : "=v"(r) : "v"(lo), "v"(hi));
  return r;
}

__device__ __forceinline__ float exp2fast(float x) {
#if __has_builtin(__builtin_amdgcn_exp2f)
  return __builtin_amdgcn_exp2f(x);
#else
  return exp2f(x);
#endif
}

__device__ __forceinline__ void lds_load16(void* lds, const void* g) {
  __builtin_amdgcn_global_load_lds(
      (const __attribute__((address_space(1))) unsigned int*)g,
      (__attribute__((address_space(3))) unsigned int*)lds,
      16, 0, 0);
}

// ---------------------------------------------------------------------------
// Kernel 1: x fp32 -> bf16 (8 elems/thread, vectorized)
// ---------------------------------------------------------------------------
__global__ __launch_bounds__(256) void conv_x_kernel(
    const float* __restrict__ x, unsigned short* __restrict__ xb) {
  int i = blockIdx.x * 256 + threadIdx.x;      // group of 8 elements
  const float4* xv = (const float4*)x;
  float4 a = xv[i * 2 + 0];
  float4 b = xv[i * 2 + 1];
  using u16x8 = __attribute__((ext_vector_type(8))) unsigned short;
  u16x8 o;
  o[0]=f2bf(a.x); o[1]=f2bf(a.y); o[2]=f2bf(a.z); o[3]=f2bf(a.w);
  o[4]=f2bf(b.x); o[5]=f2bf(b.y); o[6]=f2bf(b.z); o[7]=f2bf(b.w);
  *(u16x8*)&xb[(size_t)i * 8] = o;
}

// ---------------------------------------------------------------------------
// Kernel 2: 4 weights (K x N fp32, applied as x@W) -> W^T (N x K bf16), batched
// ---------------------------------------------------------------------------
__global__ __launch_bounds__(256) void conv_wt_kernel(
    const float* __restrict__ W0, const float* __restrict__ W1,
    const float* __restrict__ W2, const float* __restrict__ W3,
    unsigned short* __restrict__ WT) {
  __shared__ float tile[64][65];
  const float* W = (blockIdx.z == 0) ? W0 : (blockIdx.z == 1) ? W1
                 : (blockIdx.z == 2) ? W2 : W3;
  unsigned short* o = WT + (size_t)blockIdx.z * C_ * C_;
  const int k0 = blockIdx.y * 64, n0 = blockIdx.x * 64;
  const int tr = threadIdx.x >> 6;   // 0..3
  const int tc = threadIdx.x & 63;   // 0..63
#pragma unroll
  for (int i = 0; i < 16; ++i) {
    int k = tr + i * 4;
    tile[k][tc] = W[(size_t)(k0 + k) * C_ + n0 + tc];
  }
  __syncthreads();
#pragma unroll
  for (int i = 0; i < 16; ++i) {
    int n = tr + i * 4;
    o[(size_t)(n0 + n) * C_ + k0 + tc] = f2bf(tile[tc][n]);
  }
}

// ---------------------------------------------------------------------------
// Kernel 3: GEMM  C[M x N] = A[M x K] * BT[N x K]^T
// 128x128 tile, BK=32, 4 waves (2x2 of 64x64), global_load_lds staging.
// EPI 0: fused QKV epilogue -> bf16 (B,H,T,D) x3, Q scaled by log2(e)/sqrt(D)
// EPI 1: fp32 row-major + bias (output projection)
// ---------------------------------------------------------------------------
template <int EPI>
__global__ __launch_bounds__(256) void gemm128(
    const unsigned short* __restrict__ A, const unsigned short* __restrict__ BT,
    void* __restrict__ out, const float* __restrict__ bias, int K) {
  __shared__ unsigned short As[128][32];   // 8 KB
  __shared__ unsigned short Bs[128][32];   // 8 KB

  const int tid  = threadIdx.x;
  const int wid  = tid >> 6, lane = tid & 63;
  const int wr   = wid >> 1, wc = wid & 1;
  const int fr   = lane & 15, fq = lane >> 4;
  const int bm   = blockIdx.y, bn = blockIdx.x;

  const unsigned short* aP = A  + (size_t)(bm * 128 + wid * 32 + (lane >> 2)) * K + (lane & 3) * 8;
  const unsigned short* bP = BT + (size_t)(bn * 128 + wid * 32 + (lane >> 2)) * K + (lane & 3) * 8;
  unsigned short* asB = &As[wid * 32][0];
  unsigned short* bsB = &Bs[wid * 32][0];

  f32x4 acc[4][4] = {};

  for (int k0 = 0; k0 < K; k0 += 32) {
    lds_load16(asB,           aP + k0);
    lds_load16(asB + 16 * 32, aP + (size_t)16 * K + k0);
    lds_load16(bsB,           bP + k0);
    lds_load16(bsB + 16 * 32, bP + (size_t)16 * K + k0);
    __syncthreads();

    bf16x8 af[4], bfr[4];
#pragma unroll
    for (int mi = 0; mi < 4; ++mi)
      af[mi] = *(const bf16x8*)&As[wr * 64 + mi * 16 + fr][fq * 8];
#pragma unroll
    for (int ni = 0; ni < 4; ++ni)
      bfr[ni] = *(const bf16x8*)&Bs[wc * 64 + ni * 16 + fr][fq * 8];
#pragma unroll
    for (int mi = 0; mi < 4; ++mi)
#pragma unroll
      for (int ni = 0; ni < 4; ++ni)
        acc[mi][ni] = __builtin_amdgcn_mfma_f32_16x16x32_bf16(
            af[mi], bfr[ni], acc[mi][ni], 0, 0, 0);
    __syncthreads();
  }

  if (EPI == 0) {
    // fused QKV: n in [0,3072) -> matrix (Q/K/V), head, d.
    // Q scaled by log2(e)/sqrt(D) -> attention exponentials become exp2.
    unsigned short* o = (unsigned short*)out;
#pragma unroll
    for (int mi = 0; mi < 4; ++mi) {
      int m  = bm * 128 + wr * 64 + mi * 16 + fq * 4;
      int b  = m >> 11;          // T=2048
      int t0 = m & 2047;
#pragma unroll
      for (int ni = 0; ni < 4; ++ni) {
        int n = bn * 128 + wc * 64 + ni * 16 + fr;
        int mat = n >> 10;
        int nc  = n & 1023;
        int h = nc >> 6, d = nc & 63;
        float sc_ = (mat == 0) ? (0.125f * LOG2E) : 1.0f;
        size_t base = (size_t)mat * ((size_t)M_ * C_) + ((size_t)(b * H_ + h) << 17) + d;
#pragma unroll
        for (int r = 0; r < 4; ++r)
          o[base + (size_t)(t0 + r) * D_] = f2bf(acc[mi][ni][r] * sc_);
      }
    }
  } else {
    float* o = (float*)out;
#pragma unroll
    for (int mi = 0; mi < 4; ++mi) {
      int m = bm * 128 + wr * 64 + mi * 16 + fq * 4;
#pragma unroll
      for (int ni = 0; ni < 4; ++ni) {
        int n = bn * 128 + wc * 64 + ni * 16 + fr;
        float bv = bias[n];
#pragma unroll
        for (int r = 0; r < 4; ++r)
          o[(size_t)(m + r) * C_ + n] = acc[mi][ni][r] + bv;
      }
    }
  }
}

// ---------------------------------------------------------------------------
// Kernel 4: pipelined balanced causal flash attention, swapped operands.
// K fragments read DIRECTLY from global (L2/L1-resident: all 16 blocks of a
// head on one XCD), prefetched one step ahead -> no Ks LDS array at all.
// V double-buffered in LDS (transposed) -> ONE barrier per step.
// S^T = mfma(K,Q): lane holds all 16 kv of one q row -> softmax lane-local,
// l accumulated in registers (sum + 2 shfl_xor). P packed via cvt_pk_bf16.
// O^T = mfma(V^T, P^T). Grid 1024: head-per-XCD swizzle; q-tile pairs
// {pA, 31-pA} -> 33 balanced steps.
// ---------------------------------------------------------------------------
#define KSTR 72
__global__ __launch_bounds__(256, 4) void attn_kernel(
    const unsigned short* __restrict__ Qg, const unsigned short* __restrict__ Kg,
    const unsigned short* __restrict__ Vg, unsigned short* __restrict__ ctx) {
  __shared__ unsigned short VTs[2][64][KSTR];  // [buf][d][kv] transposed V
  __shared__ unsigned short Ps[4][16][KSTR];   // per-wave P tile [q][kv]

  const int tid = threadIdx.x, wid = tid >> 6, lane = tid & 63;
  const int fr = lane & 15, fq = lane >> 4;

  const int bid = blockIdx.x;
  const int xcd = bid & 7, j = bid >> 3;
  const int bh = xcd * 8 + (j & 7);          // all 16 blocks of a head on 1 XCD
  const int pA = j >> 3;                     // 0..15
  const int b = bh >> 4, h = bh & 15;
  const size_t base = (size_t)bh * (T_ * D_);

  // V staging: row per lane (d uniform per wave -> conflict-free transpose)
  const int vrow = tid & 63, vcb = (tid >> 6) * 16;
  const unsigned short* Vptr = Vg + base + (size_t)vrow * D_ + vcb;
  // K fragment base: lane (fr,fq) reads K[kv + nt*16 + fr][fq*8 + 32t]
  const unsigned short* Kfp  = Kg + base + (size_t)fr * D_ + fq * 8;

  int4 vr0, vr1;     // V tile in flight
  int4 kf[8];        // K fragments for current step [nt*2+t]

  auto vload = [&](int kv) {
    const unsigned short* vp = Vptr + (size_t)kv * D_;
    vr0 = *(const int4*)vp;
    vr1 = *(const int4*)(vp + 8);
  };
  auto kload = [&](int kv) {
#pragma unroll
    for (int nt = 0; nt < 4; ++nt)
#pragma unroll
      for (int t = 0; t < 2; ++t)
        kf[nt * 2 + t] = *(const int4*)(Kfp + (size_t)(kv + nt * 16) * D_ + t * 32);
  };
  auto stage_write = [&](int nb) {
    unsigned short vv[8];
    *(int4*)vv = vr0;
#pragma unroll
    for (int i = 0; i < 8; ++i) VTs[nb][vcb + i][vrow] = vv[i];
    *(int4*)vv = vr1;
#pragma unroll
    for (int i = 0; i < 8; ++i) VTs[nb][vcb + 8 + i][vrow] = vv[i];
  };

  vload(0);
  kload(0);
  stage_write(0);           // V tile 0 -> buf 0

  int seg = 0;
  int qb = pA * 64;
  int q0 = qb + wid * 16;

  bf16x8 qf[2];
#pragma unroll
  for (int t = 0; t < 2; ++t)
    qf[t] = *(const bf16x8*)&Qg[base + (size_t)(q0 + fr) * D_ + t * 32 + fq * 8];

  f32x4 acc[4] = {};        // O^T: d = dt*16+fq*4+reg, q = q0+fr
  float m_run = -__builtin_inff();
  float l_run = 0.f;

  __syncthreads();

  int kv0 = 0;
  for (int s = 0; s < 33; ++s) {
    const int  cur       = s & 1;
    const bool lastseg   = (kv0 == qb);
    const bool have_next = !(lastseg && seg == 1);
    const int  nkv = lastseg ? 0 : kv0 + 64;

    if (have_next) vload(nkv);             // V for next step: hides under compute

    // ---- S^T = K Q^T (lane: q=q0+fr, kv = nt*16 + fq*4 + reg) ----
    f32x4 sv[4];
    __builtin_amdgcn_s_setprio(1);
#pragma unroll
    for (int nt = 0; nt < 4; ++nt) {
      f32x4 sa = {};
      sa = __builtin_amdgcn_mfma_f32_16x16x32_bf16(
          __builtin_bit_cast(bf16x8, kf[nt * 2 + 0]), qf[0], sa, 0, 0, 0);
      sa = __builtin_amdgcn_mfma_f32_16x16x32_bf16(
          __builtin_bit_cast(bf16x8, kf[nt * 2 + 1]), qf[1], sa, 0, 0, 0);
      sv[nt] = sa;
    }
    __builtin_amdgcn_s_setprio(0);

    if (have_next) kload(nkv);             // reissue K for next step (WAR on kf)

    // ---- mask (diagonal step only) + lane-local row max ----
    float mt = -__builtin_inff();
    if (kv0 == qb) {                       // block-uniform diagonal step
      const int qi = q0 + fr;
#pragma unroll
      for (int nt = 0; nt < 4; ++nt)
#pragma unroll
        for (int r = 0; r < 4; ++r) {
          int kvi = kv0 + nt * 16 + fq * 4 + r;
          float v = sv[nt][r];
          if (kvi > qi) v = -__builtin_inff();
          sv[nt][r] = v;
          mt = fmaxf(mt, v);
        }
    } else {
#pragma unroll
      for (int nt = 0; nt < 4; ++nt)
#pragma unroll
        for (int r = 0; r < 4; ++r) mt = fmaxf(mt, sv[nt][r]);
    }
    // reduce across the 4 fq-lanes holding the same q
    mt = fmaxf(mt, __shfl_xor(mt, 16));
    mt = fmaxf(mt, __shfl_xor(mt, 32));

    // ---- defer-max: rescale only when max grew by > 8 (log2 units) ----
    if (__any(mt > m_run + 8.0f)) {
      float mn = fmaxf(m_run, mt);
      float c  = exp2fast(m_run - mn);     // first tile: exp2(-inf)=0
      m_run = mn;
#pragma unroll
      for (int dt = 0; dt < 4; ++dt) acc[dt] *= c;
      l_run *= c;
    }

    // ---- P = exp2(S - m): sum in regs (l), pack pairs, 8 x ds_write_b32 ----
    float lsum = 0.f;
#pragma unroll
    for (int nt = 0; nt < 4; ++nt)
#pragma unroll
      for (int w = 0; w < 2; ++w) {
        float p0 = exp2fast(sv[nt][2 * w]     - m_run);
        float p1 = exp2fast(sv[nt][2 * w + 1] - m_run);
        lsum += p0 + p1;
        *(unsigned*)&Ps[wid][fr][nt * 16 + fq * 4 + 2 * w] = cvt_pk_bf16(p0, p1);
      }
    lsum += __shfl_xor(lsum, 16);
    lsum += __shfl_xor(lsum, 32);
    l_run += lsum;

    // ---- O^T += V^T P^T ----
    __builtin_amdgcn_s_setprio(1);
#pragma unroll
    for (int t = 0; t < 2; ++t) {
      bf16x8 pf = *(const bf16x8*)&Ps[wid][fr][t * 32 + fq * 8];
#pragma unroll
      for (int dt = 0; dt < 4; ++dt) {
        bf16x8 vf = *(const bf16x8*)&VTs[cur][dt * 16 + fr][t * 32 + fq * 8];
        acc[dt] = __builtin_amdgcn_mfma_f32_16x16x32_bf16(vf, pf, acc[dt], 0, 0, 0);
      }
    }
    __builtin_amdgcn_s_setprio(0);

    if (have_next) stage_write(cur ^ 1);   // V next tile -> other buffer
    __syncthreads();                       // single barrier per step

    if (lastseg) {
      // ---- finalize this q-segment: lane owns q=q0+fr, 4 consecutive d ----
      float linv = 1.0f / l_run;           // all fq-lanes hold the row's l
      unsigned short* orow = ctx + (size_t)(b * T_ + q0 + fr) * C_ + h * D_;
#pragma unroll
      for (int dt = 0; dt < 4; ++dt) {
        u16x4 o;
#pragma unroll
        for (int r = 0; r < 4; ++r) o[r] = f2bf(acc[dt][r] * linv);
        *(u16x4*)&orow[dt * 16 + fq * 4] = o;
      }
      if (seg == 0) {
        seg = 1; qb = (31 - pA) * 64; q0 = qb + wid * 16;
#pragma unroll
        for (int t = 0; t < 2; ++t)
          qf[t] = *(const bf16x8*)&Qg[base + (size_t)(q0 + fr) * D_ + t * 32 + fq * 8];
#pragma unroll
        for (int dt = 0; dt < 4; ++dt) acc[dt] = f32x4{0.f, 0.f, 0.f, 0.f};
        m_run = -__builtin_inff();
        l_run = 0.f;
        kv0 = 0;
      }
    } else {
      kv0 += 64;
    }
  }
}

// ---------------------------------------------------------------------------
extern "C" void kernel_launch(void* const* d_in, const int* in_sizes, int n_in,
                              void* d_out, int out_size, void* d_ws, size_t ws_size,
                              hipStream_t stream) {
  const float* x  = (const float*)d_in[0];
  // d_in[1] = mask: exactly tril -> causality hardcoded in attn kernel
  const float* Wq = (const float*)d_in[2];
  const float* Wk = (const float*)d_in[3];
  const float* Wv = (const float*)d_in[4];
  const float* Wo = (const float*)d_in[5];
  const float* bo = (const float*)d_in[6];

  // workspace carve (all bf16/ushort elements)
  unsigned short* xb  = (unsigned short*)d_ws;     // 8192*1024
  unsigned short* wqt = xb  + (size_t)M_ * C_;     // [3072][1024] fused QKV W^T
  unsigned short* wot = wqt + (size_t)3 * C_ * C_;
  unsigned short* Qb  = wot + (size_t)C_ * C_;     // (B,H,T,D), then K, then V
  unsigned short* ctxb = xb;                       // alias: x dead after QKV

  conv_x_kernel<<<4096, 256, 0, stream>>>(x, xb);
  conv_wt_kernel<<<dim3(16, 16, 4), 256, 0, stream>>>(Wq, Wk, Wv, Wo, wqt);

  gemm128<0><<<dim3(24, M_ / 128), 256, 0, stream>>>(xb, wqt, Qb, nullptr, C_);

  attn_kernel<<<dim3(1024), 256, 0, stream>>>(
      Qb, Qb + (size_t)M_ * C_, Qb + (size_t)2 * M_ * C_, ctxb);

  gemm128<1><<<dim3(8, M_ / 128), 256, 0, stream>>>(ctxb, wot, d_out, bo, C_);
}

// Round 8
// 206.019 us; speedup vs baseline: 1.3022x; 1.3022x over previous
//
#include <hip/hip_runtime.h>
#include <hip/hip_bf16.h>

// ---------------------------------------------------------------------------
// MultiHeadAttention: x(B,T,C) fp32 -> out(B,T,C) fp32
// B=4 T=2048 C=1024 H=16 D=64. Internally bf16 MFMA with fp32 accumulation.
// Pipeline: convert -> fused QKV GEMM -> pipelined causal flash attn -> out GEMM.
// ---------------------------------------------------------------------------

#define B_  4
#define T_  2048
#define C_  1024
#define H_  16
#define D_  64
#define M_  (B_*T_)   // 8192 rows for the projection GEMMs

#define LOG2E 1.4426950408889634f

using bf16x8 = __attribute__((ext_vector_type(8))) short;
using f32x4  = __attribute__((ext_vector_type(4))) float;
using u16x4  = __attribute__((ext_vector_type(4))) unsigned short;

__device__ __forceinline__ unsigned short f2bf(float f) {
  union { float f; unsigned u; } cv; cv.f = f;
  unsigned u = cv.u;
  u += 0x7fffu + ((u >> 16) & 1u);   // RNE (inputs are finite)
  return (unsigned short)(u >> 16);
}

// pack two f32 -> one dword of 2 bf16 (RNE), single VALU op
__device__ __forceinline__ unsigned cvt_pk_bf16(float lo, float hi) {
  unsigned r;
  asm("v_cvt_pk_bf16_f32 %0, %1, %2" : "=v"(r) : "v"(lo), "v"(hi));
  return r;
}

__device__ __forceinline__ float exp2fast(float x) {
#if __has_builtin(__builtin_amdgcn_exp2f)
  return __builtin_amdgcn_exp2f(x);
#else
  return exp2f(x);
#endif
}

__device__ __forceinline__ void lds_load16(void* lds, const void* g) {
  __builtin_amdgcn_global_load_lds(
      (const __attribute__((address_space(1))) unsigned int*)g,
      (__attribute__((address_space(3))) unsigned int*)lds,
      16, 0, 0);
}

// ---------------------------------------------------------------------------
// Kernel 1: x fp32 -> bf16 (8 elems/thread, vectorized)
// ---------------------------------------------------------------------------
__global__ __launch_bounds__(256) void conv_x_kernel(
    const float* __restrict__ x, unsigned short* __restrict__ xb) {
  int i = blockIdx.x * 256 + threadIdx.x;      // group of 8 elements
  const float4* xv = (const float4*)x;
  float4 a = xv[i * 2 + 0];
  float4 b = xv[i * 2 + 1];
  using u16x8 = __attribute__((ext_vector_type(8))) unsigned short;
  u16x8 o;
  o[0]=f2bf(a.x); o[1]=f2bf(a.y); o[2]=f2bf(a.z); o[3]=f2bf(a.w);
  o[4]=f2bf(b.x); o[5]=f2bf(b.y); o[6]=f2bf(b.z); o[7]=f2bf(b.w);
  *(u16x8*)&xb[(size_t)i * 8] = o;
}

// ---------------------------------------------------------------------------
// Kernel 2: 4 weights (K x N fp32, applied as x@W) -> W^T (N x K bf16), batched
// ---------------------------------------------------------------------------
__global__ __launch_bounds__(256) void conv_wt_kernel(
    const float* __restrict__ W0, const float* __restrict__ W1,
    const float* __restrict__ W2, const float* __restrict__ W3,
    unsigned short* __restrict__ WT) {
  __shared__ float tile[64][65];
  const float* W = (blockIdx.z == 0) ? W0 : (blockIdx.z == 1) ? W1
                 : (blockIdx.z == 2) ? W2 : W3;
  unsigned short* o = WT + (size_t)blockIdx.z * C_ * C_;
  const int k0 = blockIdx.y * 64, n0 = blockIdx.x * 64;
  const int tr = threadIdx.x >> 6;   // 0..3
  const int tc = threadIdx.x & 63;   // 0..63
#pragma unroll
  for (int i = 0; i < 16; ++i) {
    int k = tr + i * 4;
    tile[k][tc] = W[(size_t)(k0 + k) * C_ + n0 + tc];
  }
  __syncthreads();
#pragma unroll
  for (int i = 0; i < 16; ++i) {
    int n = tr + i * 4;
    o[(size_t)(n0 + n) * C_ + k0 + tc] = f2bf(tile[tc][n]);
  }
}

// ---------------------------------------------------------------------------
// Kernel 3: GEMM  C[M x N] = A[M x K] * BT[N x K]^T
// 128x128 tile, BK=32, 4 waves (2x2 of 64x64), global_load_lds staging.
// EPI 0: fused QKV epilogue -> bf16 (B,H,T,D) x3, Q scaled by log2(e)/sqrt(D)
// EPI 1: fp32 row-major + bias (output projection)
// ---------------------------------------------------------------------------
template <int EPI>
__global__ __launch_bounds__(256) void gemm128(
    const unsigned short* __restrict__ A, const unsigned short* __restrict__ BT,
    void* __restrict__ out, const float* __restrict__ bias, int K) {
  __shared__ unsigned short As[128][32];   // 8 KB
  __shared__ unsigned short Bs[128][32];   // 8 KB

  const int tid  = threadIdx.x;
  const int wid  = tid >> 6, lane = tid & 63;
  const int wr   = wid >> 1, wc = wid & 1;
  const int fr   = lane & 15, fq = lane >> 4;
  const int bm   = blockIdx.y, bn = blockIdx.x;

  const unsigned short* aP = A  + (size_t)(bm * 128 + wid * 32 + (lane >> 2)) * K + (lane & 3) * 8;
  const unsigned short* bP = BT + (size_t)(bn * 128 + wid * 32 + (lane >> 2)) * K + (lane & 3) * 8;
  unsigned short* asB = &As[wid * 32][0];
  unsigned short* bsB = &Bs[wid * 32][0];

  f32x4 acc[4][4] = {};

  for (int k0 = 0; k0 < K; k0 += 32) {
    lds_load16(asB,           aP + k0);
    lds_load16(asB + 16 * 32, aP + (size_t)16 * K + k0);
    lds_load16(bsB,           bP + k0);
    lds_load16(bsB + 16 * 32, bP + (size_t)16 * K + k0);
    __syncthreads();

    bf16x8 af[4], bfr[4];
#pragma unroll
    for (int mi = 0; mi < 4; ++mi)
      af[mi] = *(const bf16x8*)&As[wr * 64 + mi * 16 + fr][fq * 8];
#pragma unroll
    for (int ni = 0; ni < 4; ++ni)
      bfr[ni] = *(const bf16x8*)&Bs[wc * 64 + ni * 16 + fr][fq * 8];
#pragma unroll
    for (int mi = 0; mi < 4; ++mi)
#pragma unroll
      for (int ni = 0; ni < 4; ++ni)
        acc[mi][ni] = __builtin_amdgcn_mfma_f32_16x16x32_bf16(
            af[mi], bfr[ni], acc[mi][ni], 0, 0, 0);
    __syncthreads();
  }

  if (EPI == 0) {
    // fused QKV: n in [0,3072) -> matrix (Q/K/V), head, d.
    // Q scaled by log2(e)/sqrt(D) -> attention exponentials become exp2.
    unsigned short* o = (unsigned short*)out;
#pragma unroll
    for (int mi = 0; mi < 4; ++mi) {
      int m  = bm * 128 + wr * 64 + mi * 16 + fq * 4;
      int b  = m >> 11;          // T=2048
      int t0 = m & 2047;
#pragma unroll
      for (int ni = 0; ni < 4; ++ni) {
        int n = bn * 128 + wc * 64 + ni * 16 + fr;
        int mat = n >> 10;
        int nc  = n & 1023;
        int h = nc >> 6, d = nc & 63;
        float sc_ = (mat == 0) ? (0.125f * LOG2E) : 1.0f;
        size_t base = (size_t)mat * ((size_t)M_ * C_) + ((size_t)(b * H_ + h) << 17) + d;
#pragma unroll
        for (int r = 0; r < 4; ++r)
          o[base + (size_t)(t0 + r) * D_] = f2bf(acc[mi][ni][r] * sc_);
      }
    }
  } else {
    float* o = (float*)out;
#pragma unroll
    for (int mi = 0; mi < 4; ++mi) {
      int m = bm * 128 + wr * 64 + mi * 16 + fq * 4;
#pragma unroll
      for (int ni = 0; ni < 4; ++ni) {
        int n = bn * 128 + wc * 64 + ni * 16 + fr;
        float bv = bias[n];
#pragma unroll
        for (int r = 0; r < 4; ++r)
          o[(size_t)(m + r) * C_ + n] = acc[mi][ni][r] + bv;
      }
    }
  }
}

// ---------------------------------------------------------------------------
// Kernel 4: pipelined balanced causal flash attention, QBLK=128.
// R4's PROVEN schedule: single-buffered K/V LDS tiles, prefetch-to-regs
// between barrier 1 and compute, regs->LDS after barrier 2 (T14).
// Each wave owns TWO 16-row q-subtiles (block = 128 q rows) so K/V LDS
// fragment reads are amortized over 2x the MFMA work.
// NaN-proof softmax by construction: NO subtile skip (fully-masked tiles
// contribute exact zeros), masking applied whenever kv0 >= subtile diag,
// every-step rescale with (mn==m_run -> c=1) guard so no inf-inf ever forms.
// Swapped operands: S^T = mfma(K,Q) -> lane-local softmax (q = row+fr);
// l in registers; P packed via cvt_pk_bf16; O^T = mfma(V^T,P^T) with V
// fragments shared across both subtiles.
// Grid 512: head-per-XCD swizzle; q-tile pairs {pA, 15-pA} -> 34 steps.
// ---------------------------------------------------------------------------
#define KSTR 72
__global__ __launch_bounds__(256) void attn_kernel(
    const unsigned short* __restrict__ Qg, const unsigned short* __restrict__ Kg,
    const unsigned short* __restrict__ Vg, unsigned short* __restrict__ ctx) {
  __shared__ unsigned short Ks[64][KSTR];       // [kv][d]            9 KB
  __shared__ unsigned short VTs[64][KSTR];      // [d][kv]            9 KB
  __shared__ unsigned short Ps[4][2][16][KSTR]; // [wave][sub][q][kv] 18 KB

  const int tid = threadIdx.x, wid = tid >> 6, lane = tid & 63;
  const int fr = lane & 15, fq = lane >> 4;

  const int bid = blockIdx.x;
  const int xcd = bid & 7, j = bid >> 3;        // j in 0..63
  const int bh = xcd * 8 + (j & 7);             // 8 heads per XCD (L2 locality)
  const int pA = j >> 3;                        // 0..7: q-tile pair {pA, 15-pA}
  const int b = bh >> 4, h = bh & 15;
  const size_t base = (size_t)bh * (T_ * D_);

  // K staging (R4): row = tid>>2, 2 x 16B chunks
  const int ksr = tid >> 2, ksc = tid & 3;
  const unsigned short* Kptr = Kg + base + (size_t)ksr * D_ + ksc * 8;
  // V staging (R4): row per lane (d uniform per wave -> conflict-free transpose)
  const int vrow = tid & 63, vcb = (tid >> 6) * 16;
  const unsigned short* Vptr = Vg + base + (size_t)vrow * D_ + vcb;

  int4 kr0, kr1, vr0, vr1;
  auto stage_load = [&](int kv) {
    const unsigned short* kp = Kptr + (size_t)kv * D_;
    kr0 = *(const int4*)kp;
    kr1 = *(const int4*)(kp + 32);
    const unsigned short* vp = Vptr + (size_t)kv * D_;
    vr0 = *(const int4*)vp;
    vr1 = *(const int4*)(vp + 8);
  };
  auto stage_write = [&]() {
    *(int4*)&Ks[ksr][ksc * 8]       = kr0;
    *(int4*)&Ks[ksr][(ksc + 4) * 8] = kr1;
    unsigned short vv[8];
    *(int4*)vv = vr0;
#pragma unroll
    for (int i = 0; i < 8; ++i) VTs[vcb + i][vrow] = vv[i];
    *(int4*)vv = vr1;
#pragma unroll
    for (int i = 0; i < 8; ++i) VTs[vcb + 8 + i][vrow] = vv[i];
  };

  stage_load(0);
  stage_write();            // tile 0 in LDS (visible after first barrier)

  int seg = 0;
  int qbase = pA * 128;

  bf16x8 qf[2][2];          // [subtile][t]
  auto qload = [&]() {
#pragma unroll
    for (int x = 0; x < 2; ++x)
#pragma unroll
      for (int t = 0; t < 2; ++t)
        qf[x][t] = *(const bf16x8*)
            &Qg[base + (size_t)(qbase + 64 * x + wid * 16 + fr) * D_ + t * 32 + fq * 8];
  };
  qload();

  f32x4 acc[2][4] = {};     // [subtile][d-tile]; O^T: q=row+fr, d=dt*16+fq*4+r
  float m_run[2] = {-__builtin_inff(), -__builtin_inff()};
  float l_run[2] = {0.f, 0.f};

  int kv0 = 0;
  for (int s = 0; s < 34; ++s) {
    const bool lastof    = (kv0 == qbase + 64);   // last kv tile of this q-tile
    const bool have_next = !(lastof && seg == 1);
    const int  nkv = lastof ? 0 : kv0 + 64;       // lastof&&seg0 -> seg1 kv=0

    __syncthreads();                              // staged tile visible
    if (have_next) stage_load(nkv);               // prefetch to regs (T14)

    // ---- K fragments (shared by both subtiles) ----
    bf16x8 kf[8];
#pragma unroll
    for (int nt = 0; nt < 4; ++nt)
#pragma unroll
      for (int t = 0; t < 2; ++t)
        kf[nt * 2 + t] = *(const bf16x8*)&Ks[nt * 16 + fr][t * 32 + fq * 8];

    // ---- per-subtile: S^T = K Q^T, softmax, P write (no skips) ----
#pragma unroll
    for (int x = 0; x < 2; ++x) {
      f32x4 sv[4];
      __builtin_amdgcn_s_setprio(1);
#pragma unroll
      for (int nt = 0; nt < 4; ++nt) {
        f32x4 sa = {};
        sa = __builtin_amdgcn_mfma_f32_16x16x32_bf16(kf[nt * 2 + 0], qf[x][0], sa, 0, 0, 0);
        sa = __builtin_amdgcn_mfma_f32_16x16x32_bf16(kf[nt * 2 + 1], qf[x][1], sa, 0, 0, 0);
        sv[nt] = sa;
      }
      __builtin_amdgcn_s_setprio(0);

      float mt = -__builtin_inff();
      if (kv0 >= qbase + 64 * x) {        // diag or beyond: apply causal mask
        const int qi = qbase + 64 * x + wid * 16 + fr;
#pragma unroll
        for (int nt = 0; nt < 4; ++nt)
#pragma unroll
          for (int r = 0; r < 4; ++r) {
            int kvi = kv0 + nt * 16 + fq * 4 + r;
            float v = sv[nt][r];
            if (kvi > qi) v = -__builtin_inff();
            sv[nt][r] = v;
            mt = fmaxf(mt, v);
          }
      } else {                            // strictly below diagonal: unmasked
#pragma unroll
        for (int nt = 0; nt < 4; ++nt)
#pragma unroll
          for (int r = 0; r < 4; ++r) mt = fmaxf(mt, sv[nt][r]);
      }
      mt = fmaxf(mt, __shfl_xor(mt, 16));
      mt = fmaxf(mt, __shfl_xor(mt, 32));

      // every-step rescale; c=1 when max unchanged (also covers mt=-inf tiles)
      {
        float mn = fmaxf(m_run[x], mt);
        float c  = (mn == m_run[x]) ? 1.0f : exp2fast(m_run[x] - mn);
        m_run[x] = mn;
#pragma unroll
        for (int dt = 0; dt < 4; ++dt) acc[x][dt] *= c;
        l_run[x] *= c;
      }

      float lsum = 0.f;
#pragma unroll
      for (int nt = 0; nt < 4; ++nt)
#pragma unroll
        for (int w = 0; w < 2; ++w) {
          float p0 = exp2fast(sv[nt][2 * w]     - m_run[x]);   // masked -> 0
          float p1 = exp2fast(sv[nt][2 * w + 1] - m_run[x]);
          lsum += p0 + p1;
          *(unsigned*)&Ps[wid][x][fr][nt * 16 + fq * 4 + 2 * w] = cvt_pk_bf16(p0, p1);
        }
      lsum += __shfl_xor(lsum, 16);
      lsum += __shfl_xor(lsum, 32);
      l_run[x] += lsum;
    }

    // ---- O^T += V^T P^T : V fragments reused across both subtiles ----
    __builtin_amdgcn_s_setprio(1);
#pragma unroll
    for (int t = 0; t < 2; ++t) {
      bf16x8 pf0 = *(const bf16x8*)&Ps[wid][0][fr][t * 32 + fq * 8];
      bf16x8 pf1 = *(const bf16x8*)&Ps[wid][1][fr][t * 32 + fq * 8];
#pragma unroll
      for (int dt = 0; dt < 4; ++dt) {
        bf16x8 vf = *(const bf16x8*)&VTs[dt * 16 + fr][t * 32 + fq * 8];
        acc[0][dt] = __builtin_amdgcn_mfma_f32_16x16x32_bf16(vf, pf0, acc[0][dt], 0, 0, 0);
        acc[1][dt] = __builtin_amdgcn_mfma_f32_16x16x32_bf16(vf, pf1, acc[1][dt], 0, 0, 0);
      }
    }
    __builtin_amdgcn_s_setprio(0);

    __syncthreads();                              // everyone done reading tile
    if (have_next) stage_write();                 // next tile -> LDS

    if (lastof) {
      // ---- finalize both subtiles of this q-tile ----
#pragma unroll
      for (int x = 0; x < 2; ++x) {
        float linv = 1.0f / l_run[x];
        unsigned short* orow =
            ctx + (size_t)(b * T_ + qbase + 64 * x + wid * 16 + fr) * C_ + h * D_;
#pragma unroll
        for (int dt = 0; dt < 4; ++dt) {
          u16x4 o;
#pragma unroll
          for (int r = 0; r < 4; ++r) o[r] = f2bf(acc[x][dt][r] * linv);
          *(u16x4*)&orow[dt * 16 + fq * 4] = o;
        }
      }
      if (seg == 0) {
        seg = 1; qbase = (15 - pA) * 128;
        qload();
#pragma unroll
        for (int x = 0; x < 2; ++x) {
#pragma unroll
          for (int dt = 0; dt < 4; ++dt) acc[x][dt] = f32x4{0.f, 0.f, 0.f, 0.f};
          m_run[x] = -__builtin_inff();
          l_run[x] = 0.f;
        }
        kv0 = 0;
      }
    } else {
      kv0 += 64;
    }
  }
}

// ---------------------------------------------------------------------------
extern "C" void kernel_launch(void* const* d_in, const int* in_sizes, int n_in,
                              void* d_out, int out_size, void* d_ws, size_t ws_size,
                              hipStream_t stream) {
  const float* x  = (const float*)d_in[0];
  // d_in[1] = mask: exactly tril -> causality hardcoded in attn kernel
  const float* Wq = (const float*)d_in[2];
  const float* Wk = (const float*)d_in[3];
  const float* Wv = (const float*)d_in[4];
  const float* Wo = (const float*)d_in[5];
  const float* bo = (const float*)d_in[6];

  // workspace carve (all bf16/ushort elements)
  unsigned short* xb  = (unsigned short*)d_ws;     // 8192*1024
  unsigned short* wqt = xb  + (size_t)M_ * C_;     // [3072][1024] fused QKV W^T
  unsigned short* wot = wqt + (size_t)3 * C_ * C_;
  unsigned short* Qb  = wot + (size_t)C_ * C_;     // (B,H,T,D), then K, then V
  unsigned short* ctxb = xb;                       // alias: x dead after QKV

  conv_x_kernel<<<4096, 256, 0, stream>>>(x, xb);
  conv_wt_kernel<<<dim3(16, 16, 4), 256, 0, stream>>>(Wq, Wk, Wv, Wo, wqt);

  gemm128<0><<<dim3(24, M_ / 128), 256, 0, stream>>>(xb, wqt, Qb, nullptr, C_);

  attn_kernel<<<dim3(512), 256, 0, stream>>>(
      Qb, Qb + (size_t)M_ * C_, Qb + (size_t)2 * M_ * C_, ctxb);

  gemm128<1><<<dim3(8, M_ / 128), 256, 0, stream>>>(ctxb, wot, d_out, bo, C_);
}

// Round 9
// 203.509 us; speedup vs baseline: 1.3183x; 1.0123x over previous
//
#include <hip/hip_runtime.h>
#include <hip/hip_bf16.h>

// ---------------------------------------------------------------------------
// MultiHeadAttention: x(B,T,C) fp32 -> out(B,T,C) fp32
// B=4 T=2048 C=1024 H=16 D=64. Internally bf16 MFMA with fp32 accumulation.
// Pipeline: convert -> fused QKV GEMM -> pipelined causal flash attn -> out GEMM.
// ---------------------------------------------------------------------------

#define B_  4
#define T_  2048
#define C_  1024
#define H_  16
#define D_  64
#define M_  (B_*T_)   // 8192 rows for the projection GEMMs

#define LOG2E 1.4426950408889634f

using bf16x8 = __attribute__((ext_vector_type(8))) short;
using f32x4  = __attribute__((ext_vector_type(4))) float;
using u16x4  = __attribute__((ext_vector_type(4))) unsigned short;

__device__ __forceinline__ unsigned short f2bf(float f) {
  union { float f; unsigned u; } cv; cv.f = f;
  unsigned u = cv.u;
  u += 0x7fffu + ((u >> 16) & 1u);   // RNE (inputs are finite)
  return (unsigned short)(u >> 16);
}

// pack two f32 -> one dword of 2 bf16 (RNE), single VALU op
__device__ __forceinline__ unsigned cvt_pk_bf16(float lo, float hi) {
  unsigned r;
  asm("v_cvt_pk_bf16_f32 %0, %1, %2" : "=v"(r) : "v"(lo), "v"(hi));
  return r;
}

__device__ __forceinline__ float exp2fast(float x) {
#if __has_builtin(__builtin_amdgcn_exp2f)
  return __builtin_amdgcn_exp2f(x);
#else
  return exp2f(x);
#endif
}

__device__ __forceinline__ void lds_load16(void* lds, const void* g) {
  __builtin_amdgcn_global_load_lds(
      (const __attribute__((address_space(1))) unsigned int*)g,
      (__attribute__((address_space(3))) unsigned int*)lds,
      16, 0, 0);
}

// ---------------------------------------------------------------------------
// Kernel 1: x fp32 -> bf16 (8 elems/thread, vectorized)
// ---------------------------------------------------------------------------
__global__ __launch_bounds__(256) void conv_x_kernel(
    const float* __restrict__ x, unsigned short* __restrict__ xb) {
  int i = blockIdx.x * 256 + threadIdx.x;      // group of 8 elements
  const float4* xv = (const float4*)x;
  float4 a = xv[i * 2 + 0];
  float4 b = xv[i * 2 + 1];
  using u16x8 = __attribute__((ext_vector_type(8))) unsigned short;
  u16x8 o;
  o[0]=f2bf(a.x); o[1]=f2bf(a.y); o[2]=f2bf(a.z); o[3]=f2bf(a.w);
  o[4]=f2bf(b.x); o[5]=f2bf(b.y); o[6]=f2bf(b.z); o[7]=f2bf(b.w);
  *(u16x8*)&xb[(size_t)i * 8] = o;
}

// ---------------------------------------------------------------------------
// Kernel 2: 4 weights (K x N fp32, applied as x@W) -> W^T (N x K bf16), batched
// ---------------------------------------------------------------------------
__global__ __launch_bounds__(256) void conv_wt_kernel(
    const float* __restrict__ W0, const float* __restrict__ W1,
    const float* __restrict__ W2, const float* __restrict__ W3,
    unsigned short* __restrict__ WT) {
  __shared__ float tile[64][65];
  const float* W = (blockIdx.z == 0) ? W0 : (blockIdx.z == 1) ? W1
                 : (blockIdx.z == 2) ? W2 : W3;
  unsigned short* o = WT + (size_t)blockIdx.z * C_ * C_;
  const int k0 = blockIdx.y * 64, n0 = blockIdx.x * 64;
  const int tr = threadIdx.x >> 6;   // 0..3
  const int tc = threadIdx.x & 63;   // 0..63
#pragma unroll
  for (int i = 0; i < 16; ++i) {
    int k = tr + i * 4;
    tile[k][tc] = W[(size_t)(k0 + k) * C_ + n0 + tc];
  }
  __syncthreads();
#pragma unroll
  for (int i = 0; i < 16; ++i) {
    int n = tr + i * 4;
    o[(size_t)(n0 + n) * C_ + k0 + tc] = f2bf(tile[tc][n]);
  }
}

// ---------------------------------------------------------------------------
// Kernel 3: GEMM  C[M x N] = A[M x K] * BT[N x K]^T
// 128x128 tile, BK=32, 4 waves (2x2 of 64x64), global_load_lds staging.
// EPI 0: fused QKV epilogue -> bf16 (B,H,T,D) x3, Q scaled by log2(e)/sqrt(D)
// EPI 1: fp32 row-major + bias (output projection)
// ---------------------------------------------------------------------------
template <int EPI>
__global__ __launch_bounds__(256) void gemm128(
    const unsigned short* __restrict__ A, const unsigned short* __restrict__ BT,
    void* __restrict__ out, const float* __restrict__ bias, int K) {
  __shared__ unsigned short As[128][32];   // 8 KB
  __shared__ unsigned short Bs[128][32];   // 8 KB

  const int tid  = threadIdx.x;
  const int wid  = tid >> 6, lane = tid & 63;
  const int wr   = wid >> 1, wc = wid & 1;
  const int fr   = lane & 15, fq = lane >> 4;
  const int bm   = blockIdx.y, bn = blockIdx.x;

  const unsigned short* aP = A  + (size_t)(bm * 128 + wid * 32 + (lane >> 2)) * K + (lane & 3) * 8;
  const unsigned short* bP = BT + (size_t)(bn * 128 + wid * 32 + (lane >> 2)) * K + (lane & 3) * 8;
  unsigned short* asB = &As[wid * 32][0];
  unsigned short* bsB = &Bs[wid * 32][0];

  f32x4 acc[4][4] = {};

  for (int k0 = 0; k0 < K; k0 += 32) {
    lds_load16(asB,           aP + k0);
    lds_load16(asB + 16 * 32, aP + (size_t)16 * K + k0);
    lds_load16(bsB,           bP + k0);
    lds_load16(bsB + 16 * 32, bP + (size_t)16 * K + k0);
    __syncthreads();

    bf16x8 af[4], bfr[4];
#pragma unroll
    for (int mi = 0; mi < 4; ++mi)
      af[mi] = *(const bf16x8*)&As[wr * 64 + mi * 16 + fr][fq * 8];
#pragma unroll
    for (int ni = 0; ni < 4; ++ni)
      bfr[ni] = *(const bf16x8*)&Bs[wc * 64 + ni * 16 + fr][fq * 8];
#pragma unroll
    for (int mi = 0; mi < 4; ++mi)
#pragma unroll
      for (int ni = 0; ni < 4; ++ni)
        acc[mi][ni] = __builtin_amdgcn_mfma_f32_16x16x32_bf16(
            af[mi], bfr[ni], acc[mi][ni], 0, 0, 0);
    __syncthreads();
  }

  if (EPI == 0) {
    // fused QKV: n in [0,3072) -> matrix (Q/K/V), head, d.
    // Q scaled by log2(e)/sqrt(D) -> attention exponentials become exp2.
    unsigned short* o = (unsigned short*)out;
#pragma unroll
    for (int mi = 0; mi < 4; ++mi) {
      int m  = bm * 128 + wr * 64 + mi * 16 + fq * 4;
      int b  = m >> 11;          // T=2048
      int t0 = m & 2047;
#pragma unroll
      for (int ni = 0; ni < 4; ++ni) {
        int n = bn * 128 + wc * 64 + ni * 16 + fr;
        int mat = n >> 10;
        int nc  = n & 1023;
        int h = nc >> 6, d = nc & 63;
        float sc_ = (mat == 0) ? (0.125f * LOG2E) : 1.0f;
        size_t base = (size_t)mat * ((size_t)M_ * C_) + ((size_t)(b * H_ + h) << 17) + d;
#pragma unroll
        for (int r = 0; r < 4; ++r)
          o[base + (size_t)(t0 + r) * D_] = f2bf(acc[mi][ni][r] * sc_);
      }
    }
  } else {
    float* o = (float*)out;
#pragma unroll
    for (int mi = 0; mi < 4; ++mi) {
      int m = bm * 128 + wr * 64 + mi * 16 + fq * 4;
#pragma unroll
      for (int ni = 0; ni < 4; ++ni) {
        int n = bn * 128 + wc * 64 + ni * 16 + fr;
        float bv = bias[n];
#pragma unroll
        for (int r = 0; r < 4; ++r)
          o[(size_t)(m + r) * C_ + n] = acc[mi][ni][r] + bv;
      }
    }
  }
}

// ---------------------------------------------------------------------------
// Kernel 4: pipelined balanced causal flash attention, QBLK=128.
// R8's PASSING structure frozen (2 barriers, stage-to-regs early / LDS-write
// late, no subtile skips, kv0>=diag masking, every-step guarded rescale).
// R9 deltas (LDS instruction-count only):
//  - V staged PACKED: thread (vc,vr_) loads kv rows {2vr_,2vr_+1} at d-chunk
//    vc*8 and writes one b32 per d -> 8 writes/thread (was 16 scalar b16).
//  - P written as uint2 (b64): the two cvt_pk dwords per nt are adjacent
//    and 8B-aligned -> 4 writes/subtile (was 8 b32).
// Swapped operands: S^T = mfma(K,Q) -> lane-local softmax (q = row+fr);
// l in registers; P packed via cvt_pk_bf16; O^T = mfma(V^T,P^T) with V/K
// fragments shared across both subtiles.
// Grid 512: head-per-XCD swizzle; q-tile pairs {pA, 15-pA} -> 34 steps.
// ---------------------------------------------------------------------------
#define KSTR 72
__global__ __launch_bounds__(256) void attn_kernel(
    const unsigned short* __restrict__ Qg, const unsigned short* __restrict__ Kg,
    const unsigned short* __restrict__ Vg, unsigned short* __restrict__ ctx) {
  __shared__ __align__(16) unsigned short Ks[64][KSTR];       // [kv][d]    9 KB
  __shared__ __align__(16) unsigned short VTs[64][KSTR];      // [d][kv]    9 KB
  __shared__ __align__(16) unsigned short Ps[4][2][16][KSTR]; // [w][x][q][kv]

  const int tid = threadIdx.x, wid = tid >> 6, lane = tid & 63;
  const int fr = lane & 15, fq = lane >> 4;

  const int bid = blockIdx.x;
  const int xcd = bid & 7, j = bid >> 3;        // j in 0..63
  const int bh = xcd * 8 + (j & 7);             // 8 heads per XCD (L2 locality)
  const int pA = j >> 3;                        // 0..7: q-tile pair {pA, 15-pA}
  const int b = bh >> 4, h = bh & 15;
  const size_t base = (size_t)bh * (T_ * D_);

  // K staging: row = tid>>2, 2 x 16B chunks
  const int ksr = tid >> 2, ksc = tid & 3;
  const unsigned short* Kptr = Kg + base + (size_t)ksr * D_ + ksc * 8;
  // V staging (packed): thread (vc,vr_) handles kv rows 2vr_,2vr_+1, d vc*8..+7
  const int vc = tid >> 5, vr_ = tid & 31;
  const unsigned short* Vptr = Vg + base + (size_t)(2 * vr_) * D_ + vc * 8;

  int4 kr0, kr1, va, vb;
  auto stage_load = [&](int kv) {
    const unsigned short* kp = Kptr + (size_t)kv * D_;
    kr0 = *(const int4*)kp;
    kr1 = *(const int4*)(kp + 32);
    const unsigned short* vp = Vptr + (size_t)kv * D_;
    va = *(const int4*)vp;          // kv row 2vr_
    vb = *(const int4*)(vp + D_);   // kv row 2vr_+1
  };
  auto stage_write = [&]() {
    *(int4*)&Ks[ksr][ksc * 8]       = kr0;
    *(int4*)&Ks[ksr][(ksc + 4) * 8] = kr1;
    const unsigned short* pa = (const unsigned short*)&va;
    const unsigned short* pb = (const unsigned short*)&vb;
#pragma unroll
    for (int i = 0; i < 8; ++i) {
      unsigned w = (unsigned)pa[i] | ((unsigned)pb[i] << 16);
      *(unsigned*)&VTs[vc * 8 + i][2 * vr_] = w;   // kv pair packed in one b32
    }
  };

  stage_load(0);
  stage_write();            // tile 0 in LDS (visible after first barrier)

  int seg = 0;
  int qbase = pA * 128;

  bf16x8 qf[2][2];          // [subtile][t]
  auto qload = [&]() {
#pragma unroll
    for (int x = 0; x < 2; ++x)
#pragma unroll
      for (int t = 0; t < 2; ++t)
        qf[x][t] = *(const bf16x8*)
            &Qg[base + (size_t)(qbase + 64 * x + wid * 16 + fr) * D_ + t * 32 + fq * 8];
  };
  qload();

  f32x4 acc[2][4] = {};     // [subtile][d-tile]; O^T: q=row+fr, d=dt*16+fq*4+r
  float m_run[2] = {-__builtin_inff(), -__builtin_inff()};
  float l_run[2] = {0.f, 0.f};

  int kv0 = 0;
  for (int s = 0; s < 34; ++s) {
    const bool lastof    = (kv0 == qbase + 64);   // last kv tile of this q-tile
    const bool have_next = !(lastof && seg == 1);
    const int  nkv = lastof ? 0 : kv0 + 64;       // lastof&&seg0 -> seg1 kv=0

    __syncthreads();                              // staged tile visible
    if (have_next) stage_load(nkv);               // prefetch to regs (T14)

    // ---- K fragments (shared by both subtiles) ----
    bf16x8 kf[8];
#pragma unroll
    for (int nt = 0; nt < 4; ++nt)
#pragma unroll
      for (int t = 0; t < 2; ++t)
        kf[nt * 2 + t] = *(const bf16x8*)&Ks[nt * 16 + fr][t * 32 + fq * 8];

    // ---- per-subtile: S^T = K Q^T, softmax, P write (no skips) ----
#pragma unroll
    for (int x = 0; x < 2; ++x) {
      f32x4 sv[4];
      __builtin_amdgcn_s_setprio(1);
#pragma unroll
      for (int nt = 0; nt < 4; ++nt) {
        f32x4 sa = {};
        sa = __builtin_amdgcn_mfma_f32_16x16x32_bf16(kf[nt * 2 + 0], qf[x][0], sa, 0, 0, 0);
        sa = __builtin_amdgcn_mfma_f32_16x16x32_bf16(kf[nt * 2 + 1], qf[x][1], sa, 0, 0, 0);
        sv[nt] = sa;
      }
      __builtin_amdgcn_s_setprio(0);

      float mt = -__builtin_inff();
      if (kv0 >= qbase + 64 * x) {        // diag or beyond: apply causal mask
        const int qi = qbase + 64 * x + wid * 16 + fr;
#pragma unroll
        for (int nt = 0; nt < 4; ++nt)
#pragma unroll
          for (int r = 0; r < 4; ++r) {
            int kvi = kv0 + nt * 16 + fq * 4 + r;
            float v = sv[nt][r];
            if (kvi > qi) v = -__builtin_inff();
            sv[nt][r] = v;
            mt = fmaxf(mt, v);
          }
      } else {                            // strictly below diagonal: unmasked
#pragma unroll
        for (int nt = 0; nt < 4; ++nt)
#pragma unroll
          for (int r = 0; r < 4; ++r) mt = fmaxf(mt, sv[nt][r]);
      }
      mt = fmaxf(mt, __shfl_xor(mt, 16));
      mt = fmaxf(mt, __shfl_xor(mt, 32));

      // every-step rescale; c=1 when max unchanged (also covers mt=-inf tiles)
      {
        float mn = fmaxf(m_run[x], mt);
        float c  = (mn == m_run[x]) ? 1.0f : exp2fast(m_run[x] - mn);
        m_run[x] = mn;
#pragma unroll
        for (int dt = 0; dt < 4; ++dt) acc[x][dt] *= c;
        l_run[x] *= c;
      }

      float lsum = 0.f;
#pragma unroll
      for (int nt = 0; nt < 4; ++nt) {
        float p0 = exp2fast(sv[nt][0] - m_run[x]);   // masked -> 0
        float p1 = exp2fast(sv[nt][1] - m_run[x]);
        float p2 = exp2fast(sv[nt][2] - m_run[x]);
        float p3 = exp2fast(sv[nt][3] - m_run[x]);
        lsum += (p0 + p1) + (p2 + p3);
        uint2 pk;
        pk.x = cvt_pk_bf16(p0, p1);
        pk.y = cvt_pk_bf16(p2, p3);
        *(uint2*)&Ps[wid][x][fr][nt * 16 + fq * 4] = pk;   // one b64 store
      }
      lsum += __shfl_xor(lsum, 16);
      lsum += __shfl_xor(lsum, 32);
      l_run[x] += lsum;
    }

    // ---- O^T += V^T P^T : V fragments reused across both subtiles ----
    __builtin_amdgcn_s_setprio(1);
#pragma unroll
    for (int t = 0; t < 2; ++t) {
      bf16x8 pf0 = *(const bf16x8*)&Ps[wid][0][fr][t * 32 + fq * 8];
      bf16x8 pf1 = *(const bf16x8*)&Ps[wid][1][fr][t * 32 + fq * 8];
#pragma unroll
      for (int dt = 0; dt < 4; ++dt) {
        bf16x8 vf = *(const bf16x8*)&VTs[dt * 16 + fr][t * 32 + fq * 8];
        acc[0][dt] = __builtin_amdgcn_mfma_f32_16x16x32_bf16(vf, pf0, acc[0][dt], 0, 0, 0);
        acc[1][dt] = __builtin_amdgcn_mfma_f32_16x16x32_bf16(vf, pf1, acc[1][dt], 0, 0, 0);
      }
    }
    __builtin_amdgcn_s_setprio(0);

    __syncthreads();                              // everyone done reading tile
    if (have_next) stage_write();                 // next tile -> LDS

    if (lastof) {
      // ---- finalize both subtiles of this q-tile ----
#pragma unroll
      for (int x = 0; x < 2; ++x) {
        float linv = 1.0f / l_run[x];
        unsigned short* orow =
            ctx + (size_t)(b * T_ + qbase + 64 * x + wid * 16 + fr) * C_ + h * D_;
#pragma unroll
        for (int dt = 0; dt < 4; ++dt) {
          u16x4 o;
#pragma unroll
          for (int r = 0; r < 4; ++r) o[r] = f2bf(acc[x][dt][r] * linv);
          *(u16x4*)&orow[dt * 16 + fq * 4] = o;
        }
      }
      if (seg == 0) {
        seg = 1; qbase = (15 - pA) * 128;
        qload();
#pragma unroll
        for (int x = 0; x < 2; ++x) {
#pragma unroll
          for (int dt = 0; dt < 4; ++dt) acc[x][dt] = f32x4{0.f, 0.f, 0.f, 0.f};
          m_run[x] = -__builtin_inff();
          l_run[x] = 0.f;
        }
        kv0 = 0;
      }
    } else {
      kv0 += 64;
    }
  }
}

// ---------------------------------------------------------------------------
extern "C" void kernel_launch(void* const* d_in, const int* in_sizes, int n_in,
                              void* d_out, int out_size, void* d_ws, size_t ws_size,
                              hipStream_t stream) {
  const float* x  = (const float*)d_in[0];
  // d_in[1] = mask: exactly tril -> causality hardcoded in attn kernel
  const float* Wq = (const float*)d_in[2];
  const float* Wk = (const float*)d_in[3];
  const float* Wv = (const float*)d_in[4];
  const float* Wo = (const float*)d_in[5];
  const float* bo = (const float*)d_in[6];

  // workspace carve (all bf16/ushort elements)
  unsigned short* xb  = (unsigned short*)d_ws;     // 8192*1024
  unsigned short* wqt = xb  + (size_t)M_ * C_;     // [3072][1024] fused QKV W^T
  unsigned short* wot = wqt + (size_t)3 * C_ * C_;
  unsigned short* Qb  = wot + (size_t)C_ * C_;     // (B,H,T,D), then K, then V
  unsigned short* ctxb = xb;                       // alias: x dead after QKV

  conv_x_kernel<<<4096, 256, 0, stream>>>(x, xb);
  conv_wt_kernel<<<dim3(16, 16, 4), 256, 0, stream>>>(Wq, Wk, Wv, Wo, wqt);

  gemm128<0><<<dim3(24, M_ / 128), 256, 0, stream>>>(xb, wqt, Qb, nullptr, C_);

  attn_kernel<<<dim3(512), 256, 0, stream>>>(
      Qb, Qb + (size_t)M_ * C_, Qb + (size_t)2 * M_ * C_, ctxb);

  gemm128<1><<<dim3(8, M_ / 128), 256, 0, stream>>>(ctxb, wot, d_out, bo, C_);
}